// Round 18
// baseline (99.544 us; speedup 1.0000x reference)
//
#include <hip/hip_runtime.h>

#define NN 8192
#define DD 64
#define NL 3
#define LOG2E 1.4426950408889634f

typedef _Float16 f16x8 __attribute__((ext_vector_type(8)));
typedef _Float16 f16x2 __attribute__((ext_vector_type(2)));
typedef float f32x2 __attribute__((ext_vector_type(2)));
typedef float f32x16 __attribute__((ext_vector_type(16)));

union F16U { f16x8 v8; f16x2 h2[4]; };

// Prep kernel (unchanged).
//   a=(f1+ba)*log2e, b=f2*log2e
//   Rt[l][i]=2^(-0.8a) f32; E2h[l][j]=2^(b-4) f16; E2sh[l][j]=2^(0.2b-4) f16
//   e_l = 2^(a+4) * m_l, m_l = max(E2h, Rt*E2sh); row scale cancels exactly.
__global__ __launch_bounds__(256) void mas_prep(const float* __restrict__ X,
                                                const float* __restrict__ Ws,
                                                const float* __restrict__ bWs,
                                                const float* __restrict__ a1,
                                                const float* __restrict__ a2,
                                                const float* __restrict__ ba,
                                                float* __restrict__ Rt,
                                                _Float16* __restrict__ E2h,
                                                _Float16* __restrict__ E2sh,
                                                _Float16* __restrict__ Xf) {
    if (blockIdx.x < 96) {
        const int l = blockIdx.x >> 5;
        const int i = ((blockIdx.x & 31) << 8) + threadIdx.x;

        float xr[DD];
        const float4* X4 = (const float4*)(X + (size_t)i * DD);
#pragma unroll
        for (int q = 0; q < DD / 4; ++q) {
            float4 v = X4[q];
            xr[4 * q + 0] = v.x; xr[4 * q + 1] = v.y;
            xr[4 * q + 2] = v.z; xr[4 * q + 3] = v.w;
        }

        const float* W   = Ws  + l * DD * DD;
        const float* a1l = a1  + l * DD;
        const float* a2l = a2  + l * DD;
        const float* bwl = bWs + l * DD;

        float f1 = 0.f, f2 = 0.f;
#pragma unroll 4
        for (int d = 0; d < DD; ++d) {
            float wh = bwl[d];
            const float* wr = W + d * DD;
#pragma unroll
            for (int k = 0; k < DD; ++k) wh = fmaf(xr[k], wr[k], wh);
            f1 = fmaf(wh, a1l[d], f1);
            f2 = fmaf(wh, a2l[d], f2);
        }
        const float a = (f1 + ba[l]) * LOG2E;
        const float b = f2 * LOG2E;
        Rt  [l * NN + i] = exp2f(-0.8f * a);
        E2h [l * NN + i] = (_Float16)exp2f(b - 4.0f);
        E2sh[l * NN + i] = (_Float16)exp2f(0.2f * b - 4.0f);
    } else {
        const int t = (blockIdx.x - 96) * 256 + threadIdx.x;   // 0..65535
        const int lane = t & 63;
        const int st = t >> 6;
        const int S = st >> 1, tl = st & 1;
        const int d = tl * 32 + (lane & 31);
        const int j0 = S * 16 + (lane >> 5) * 8;
        f16x8 v;
#pragma unroll
        for (int e = 0; e < 8; ++e) v[e] = (_Float16)X[(size_t)(j0 + e) * DD + d];
        *(f16x8*)(Xf + (size_t)t * 8) = v;
    }
}

// Main v18 = R15 body + fused finalize: after writing partials, blocks take a
// per-tile ticket (device-scope atomic); the LAST of the 4 j-split blocks
// re-reads all 4 partials in FIXED q-order (deterministic, same summation
// order as the old comb kernel) while L2-warm, normalizes, writes out.
__global__ __launch_bounds__(256, 3) void mas_main18(const _Float16* __restrict__ Xf,
                                                     const float* __restrict__ Rt,
                                                     const _Float16* __restrict__ E2h,
                                                     const _Float16* __restrict__ E2sh,
                                                     float* __restrict__ numpart,
                                                     float* __restrict__ zpart,
                                                     int* __restrict__ ticket,
                                                     float* __restrict__ out) {
    __shared__ float red[4][64][33];    // aliased as staged tables during loop
    __shared__ float zred[4][3][64];
    __shared__ float zf[3][64];
    __shared__ int lastflag;

    const int tid  = threadIdx.x;
    const int lane = tid & 63;
    const int wv   = tid >> 6;
    const int hi   = lane >> 5;
    const int row  = lane & 31;
    const int rt   = blockIdx.x;       // 64-row tile
    const int q    = blockIdx.y;
    const int iA   = rt * 64 + row;
    const int iB   = iA + 32;

#define MKP(x) {(_Float16)(x), (_Float16)(x)}
    const f16x2 R0A = MKP(Rt[0*NN+iA]), R1A = MKP(Rt[1*NN+iA]), R2A = MKP(Rt[2*NN+iA]);
    const f16x2 R0B = MKP(Rt[0*NN+iB]), R1B = MKP(Rt[1*NN+iB]), R2B = MKP(Rt[2*NN+iB]);
#undef MKP

    constexpr int NQB = 4;
    constexpr int jspan = NN / NQB;
    constexpr int wspan = jspan >> 2;
    constexpr int nst   = wspan >> 4;   // 32
    const int jblk  = q * jspan;

    // ---- stage 6 table streams into LDS (24KB) ----
    _Float16* tab = (_Float16*)&red[0][0][0];
    {
        const _Float16* s0 = E2h  + 0 * NN + jblk;
        const _Float16* s1 = E2h  + 1 * NN + jblk;
        const _Float16* s2 = E2h  + 2 * NN + jblk;
        const _Float16* s3 = E2sh + 0 * NN + jblk;
        const _Float16* s4 = E2sh + 1 * NN + jblk;
        const _Float16* s5 = E2sh + 2 * NN + jblk;
        *(f16x8*)&tab[0 * jspan + tid * 8] = *(const f16x8*)(s0 + tid * 8);
        *(f16x8*)&tab[1 * jspan + tid * 8] = *(const f16x8*)(s1 + tid * 8);
        *(f16x8*)&tab[2 * jspan + tid * 8] = *(const f16x8*)(s2 + tid * 8);
        *(f16x8*)&tab[3 * jspan + tid * 8] = *(const f16x8*)(s3 + tid * 8);
        *(f16x8*)&tab[4 * jspan + tid * 8] = *(const f16x8*)(s4 + tid * 8);
        *(f16x8*)&tab[5 * jspan + tid * 8] = *(const f16x8*)(s5 + tid * 8);
    }
    __syncthreads();

    const int tloc0 = wv * wspan + hi * 8;
    const f16x8* pB = (const f16x8*)Xf + (size_t)((jblk + wv * wspan) >> 4) * 128 + lane;

    f32x16 a00 = {}, a01 = {}, a10 = {}, a11 = {};
    f32x2 z0A = {0,0}, z1A = {0,0}, z2A = {0,0};
    f32x2 z0B = {0,0}, z1B = {0,0}, z2B = {0,0};

#pragma unroll 2
    for (int s = 0; s < nst; ++s) {
        const int o = tloc0 + s * 16;
        F16U g0, g1, g2, h0, h1, h2v;
        g0.v8  = *(const f16x8*)&tab[0 * jspan + o];
        g1.v8  = *(const f16x8*)&tab[1 * jspan + o];
        g2.v8  = *(const f16x8*)&tab[2 * jspan + o];
        h0.v8  = *(const f16x8*)&tab[3 * jspan + o];
        h1.v8  = *(const f16x8*)&tab[4 * jspan + o];
        h2v.v8 = *(const f16x8*)&tab[5 * jspan + o];
        const f16x8 vb0 = pB[s * 128];
        const f16x8 vb1 = pB[s * 128 + 64];

        // ---- half A ----
        {
            f16x2 m0[4], m1[4], m2[4];
#pragma unroll
            for (int g = 0; g < 4; ++g) {
                m0[g] = __builtin_elementwise_max(g0.h2[g], R0A * h0.h2[g]);
                m1[g] = __builtin_elementwise_max(g1.h2[g], R1A * h1.h2[g]);
                m2[g] = __builtin_elementwise_max(g2.h2[g], R2A * h2v.h2[g]);
            }
            const f16x2 t0 = (m0[0] + m0[1]) + (m0[2] + m0[3]);
            const f16x2 t1 = (m1[0] + m1[1]) + (m1[2] + m1[3]);
            const f16x2 t2 = (m2[0] + m2[1]) + (m2[2] + m2[3]);
            z0A += (f32x2){(float)t0[0], (float)t0[1]};
            z1A += (f32x2){(float)t1[0], (float)t1[1]};
            z2A += (f32x2){(float)t2[0], (float)t2[1]};
            F16U wa;
#pragma unroll
            for (int g = 0; g < 4; ++g) wa.h2[g] = m0[g] * (m1[g] * m2[g]);
            a00 = __builtin_amdgcn_mfma_f32_32x32x16_f16(wa.v8, vb0, a00, 0, 0, 0);
            a01 = __builtin_amdgcn_mfma_f32_32x32x16_f16(wa.v8, vb1, a01, 0, 0, 0);
        }
        // ---- half B ----
        {
            f16x2 m0[4], m1[4], m2[4];
#pragma unroll
            for (int g = 0; g < 4; ++g) {
                m0[g] = __builtin_elementwise_max(g0.h2[g], R0B * h0.h2[g]);
                m1[g] = __builtin_elementwise_max(g1.h2[g], R1B * h1.h2[g]);
                m2[g] = __builtin_elementwise_max(g2.h2[g], R2B * h2v.h2[g]);
            }
            const f16x2 t0 = (m0[0] + m0[1]) + (m0[2] + m0[3]);
            const f16x2 t1 = (m1[0] + m1[1]) + (m1[2] + m1[3]);
            const f16x2 t2 = (m2[0] + m2[1]) + (m2[2] + m2[3]);
            z0B += (f32x2){(float)t0[0], (float)t0[1]};
            z1B += (f32x2){(float)t1[0], (float)t1[1]};
            z2B += (f32x2){(float)t2[0], (float)t2[1]};
            F16U wa;
#pragma unroll
            for (int g = 0; g < 4; ++g) wa.h2[g] = m0[g] * (m1[g] * m2[g]);
            a10 = __builtin_amdgcn_mfma_f32_32x32x16_f16(wa.v8, vb0, a10, 0, 0, 0);
            a11 = __builtin_amdgcn_mfma_f32_32x32x16_f16(wa.v8, vb1, a11, 0, 0, 0);
        }
    }

    float z0a = z0A[0] + z0A[1], z1a = z1A[0] + z1A[1], z2a = z2A[0] + z2A[1];
    float z0b = z0B[0] + z0B[1], z1b = z1B[0] + z1B[1], z2b = z2B[0] + z2B[1];
    z0a += __shfl_xor(z0a, 32); z1a += __shfl_xor(z1a, 32); z2a += __shfl_xor(z2a, 32);
    z0b += __shfl_xor(z0b, 32); z1b += __shfl_xor(z1b, 32); z2b += __shfl_xor(z2b, 32);

    __syncthreads();   // all waves done reading tab before red is overwritten

    if (lane < 32) {
        zred[wv][0][row] = z0a; zred[wv][1][row] = z1a; zred[wv][2][row] = z2a;
        zred[wv][0][row + 32] = z0b; zred[wv][1][row + 32] = z1b; zred[wv][2][row + 32] = z2b;
    }

    // ---- epilogue pass 1: half A (global rows rt*64+0..31) ----
#pragma unroll
    for (int g = 0; g < 4; ++g) {
        const int rb = 8 * g + 4 * hi;
        *(float4*)&red[wv][row][rb] =
            make_float4(a00[4*g], a00[4*g+1], a00[4*g+2], a00[4*g+3]);
        *(float4*)&red[wv][row + 32][rb] =
            make_float4(a01[4*g], a01[4*g+1], a01[4*g+2], a01[4*g+3]);
    }
    __syncthreads();

    if (tid < 192) {
        const int l = tid >> 6, r = tid & 63;
        const float Z = zred[0][l][r] + zred[1][l][r] + zred[2][l][r] + zred[3][l][r];
        zpart[((size_t)q * 3 + l) * NN + rt * 64 + r] = Z;
    }

    {
        const int col = tid & 63;
        const int r0 = (tid >> 6) * 8;
        float s[8] = {0,0,0,0,0,0,0,0};
#pragma unroll
        for (int w = 0; w < 4; ++w) {
            const float4 u = *(const float4*)&red[w][col][r0];
            const float4 v = *(const float4*)&red[w][col][r0 + 4];
            s[0] += u.x; s[1] += u.y; s[2] += u.z; s[3] += u.w;
            s[4] += v.x; s[5] += v.y; s[6] += v.z; s[7] += v.w;
        }
        float* np = numpart + (size_t)q * NN * DD;
#pragma unroll
        for (int u2 = 0; u2 < 8; ++u2)
            np[(size_t)(rt * 64 + r0 + u2) * DD + col] = s[u2];
    }
    __syncthreads();

    // ---- epilogue pass 2: half B (global rows rt*64+32..63) ----
#pragma unroll
    for (int g = 0; g < 4; ++g) {
        const int rb = 8 * g + 4 * hi;
        *(float4*)&red[wv][row][rb] =
            make_float4(a10[4*g], a10[4*g+1], a10[4*g+2], a10[4*g+3]);
        *(float4*)&red[wv][row + 32][rb] =
            make_float4(a11[4*g], a11[4*g+1], a11[4*g+2], a11[4*g+3]);
    }
    __syncthreads();

    {
        const int col = tid & 63;
        const int r0 = (tid >> 6) * 8;
        float s[8] = {0,0,0,0,0,0,0,0};
#pragma unroll
        for (int w = 0; w < 4; ++w) {
            const float4 u = *(const float4*)&red[w][col][r0];
            const float4 v = *(const float4*)&red[w][col][r0 + 4];
            s[0] += u.x; s[1] += u.y; s[2] += u.z; s[3] += u.w;
            s[4] += v.x; s[5] += v.y; s[6] += v.z; s[7] += v.w;
        }
        float* np = numpart + (size_t)q * NN * DD;
#pragma unroll
        for (int u2 = 0; u2 < 8; ++u2)
            np[(size_t)(rt * 64 + 32 + r0 + u2) * DD + col] = s[u2];
    }

    // ---- fused finalize: last block of this tile sums partials (fixed order) ----
    __threadfence();                     // release: partials visible device-wide
    if (tid == 0)
        lastflag = (atomicAdd(&ticket[rt], 1) == NQB - 1);
    __syncthreads();
    if (!lastflag) return;
    __threadfence();                     // acquire: don't read stale partials

    if (tid < 192) {
        const int l = tid >> 6, r = tid & 63;
        float Z = 0.f;
#pragma unroll
        for (int qq = 0; qq < NQB; ++qq)
            Z += zpart[((size_t)qq * 3 + l) * NN + rt * 64 + r];
        zf[l][r] = Z;
    }
    __syncthreads();

    {
        const int col = tid & 63;
        const int rg = tid >> 6;         // 0..3
#pragma unroll
        for (int k = 0; k < 16; ++k) {
            const int r = rg * 16 + k;
            const size_t off = (size_t)(rt * 64 + r) * DD + col;
            float s = 0.f;
#pragma unroll
            for (int qq = 0; qq < NQB; ++qq)
                s += numpart[(size_t)qq * NN * DD + off];
            out[off] = s / (zf[0][r] * (zf[1][r] * zf[2][r]));
        }
    }
}

// Fallback main (runtime nqb, VMEM tables) for small-ws case.
__global__ __launch_bounds__(256, 4) void mas_main_fb(const _Float16* __restrict__ Xf,
                                                      const float* __restrict__ Rt,
                                                      const _Float16* __restrict__ E2h,
                                                      const _Float16* __restrict__ E2sh,
                                                      float* __restrict__ numpart,
                                                      float* __restrict__ zpart,
                                                      float* __restrict__ out,
                                                      int nqb) {
    __shared__ float red[4][64][33];
    __shared__ float zred[4][3][32];
    __shared__ float zfin[3][32];

    const int tid  = threadIdx.x;
    const int lane = tid & 63;
    const int wv   = tid >> 6;
    const int hi   = lane >> 5;
    const int row  = lane & 31;
    const int rt   = blockIdx.x;
    const int q    = blockIdx.y;
    const int i    = rt * 32 + row;

    const float r0f = Rt[0 * NN + i], r1f = Rt[1 * NN + i], r2f = Rt[2 * NN + i];
    const f16x2 R0p = {(_Float16)r0f, (_Float16)r0f};
    const f16x2 R1p = {(_Float16)r1f, (_Float16)r1f};
    const f16x2 R2p = {(_Float16)r2f, (_Float16)r2f};

    const int jspan = NN / nqb;
    const int wspan = jspan >> 2;
    const int jbase = q * jspan + wv * wspan;
    const int nst   = wspan >> 4;

    const _Float16* q20 = E2h  + 0 * NN + jbase + hi * 8;
    const _Float16* q21 = E2h  + 1 * NN + jbase + hi * 8;
    const _Float16* q22 = E2h  + 2 * NN + jbase + hi * 8;
    const _Float16* r20 = E2sh + 0 * NN + jbase + hi * 8;
    const _Float16* r21 = E2sh + 1 * NN + jbase + hi * 8;
    const _Float16* r22 = E2sh + 2 * NN + jbase + hi * 8;
    const f16x8* pB = (const f16x8*)Xf + (size_t)(jbase >> 4) * 128 + lane;

    f32x16 acc0 = {};
    f32x16 acc1 = {};
    f32x2 z0p = {0.f, 0.f}, z1p = {0.f, 0.f}, z2p = {0.f, 0.f};

    for (int s = 0; s < nst; ++s) {
        const int o = s * 16;
        F16U g0, g1, g2, h0, h1, h2v;
        g0.v8  = *(const f16x8*)(q20 + o);
        g1.v8  = *(const f16x8*)(q21 + o);
        g2.v8  = *(const f16x8*)(q22 + o);
        h0.v8  = *(const f16x8*)(r20 + o);
        h1.v8  = *(const f16x8*)(r21 + o);
        h2v.v8 = *(const f16x8*)(r22 + o);
        const f16x8 vb0 = pB[s * 128];
        const f16x8 vb1 = pB[s * 128 + 64];

        f16x2 m0[4], m1[4], m2[4];
#pragma unroll
        for (int g = 0; g < 4; ++g) {
            m0[g] = __builtin_elementwise_max(g0.h2[g], R0p * h0.h2[g]);
            m1[g] = __builtin_elementwise_max(g1.h2[g], R1p * h1.h2[g]);
            m2[g] = __builtin_elementwise_max(g2.h2[g], R2p * h2v.h2[g]);
        }
        const f16x2 t0 = (m0[0] + m0[1]) + (m0[2] + m0[3]);
        const f16x2 t1 = (m1[0] + m1[1]) + (m1[2] + m1[3]);
        const f16x2 t2 = (m2[0] + m2[1]) + (m2[2] + m2[3]);
        z0p += (f32x2){(float)t0[0], (float)t0[1]};
        z1p += (f32x2){(float)t1[0], (float)t1[1]};
        z2p += (f32x2){(float)t2[0], (float)t2[1]};

        F16U wa;
#pragma unroll
        for (int g = 0; g < 4; ++g) wa.h2[g] = m0[g] * (m1[g] * m2[g]);

        acc0 = __builtin_amdgcn_mfma_f32_32x32x16_f16(wa.v8, vb0, acc0, 0, 0, 0);
        acc1 = __builtin_amdgcn_mfma_f32_32x32x16_f16(wa.v8, vb1, acc1, 0, 0, 0);
    }

    float z0 = z0p[0] + z0p[1];
    float z1 = z1p[0] + z1p[1];
    float z2 = z2p[0] + z2p[1];
    z0 += __shfl_xor(z0, 32);
    z1 += __shfl_xor(z1, 32);
    z2 += __shfl_xor(z2, 32);

#pragma unroll
    for (int g = 0; g < 4; ++g) {
        const int rb = 8 * g + 4 * hi;
        *(float4*)&red[wv][row][rb] =
            make_float4(acc0[4 * g], acc0[4 * g + 1], acc0[4 * g + 2], acc0[4 * g + 3]);
        *(float4*)&red[wv][row + 32][rb] =
            make_float4(acc1[4 * g], acc1[4 * g + 1], acc1[4 * g + 2], acc1[4 * g + 3]);
    }
    if (lane < 32) {
        zred[wv][0][row] = z0; zred[wv][1][row] = z1; zred[wv][2][row] = z2;
    }
    __syncthreads();

    if (tid < 96) {
        const int l = tid >> 5, r = tid & 31;
        const float Z = zred[0][l][r] + zred[1][l][r] + zred[2][l][r] + zred[3][l][r];
        if (nqb > 1) zpart[((size_t)q * 3 + l) * NN + rt * 32 + r] = Z;
        else zfin[l][r] = Z;
    }
    __syncthreads();

    {
        const int col = tid & 63;
        const int r0 = (tid >> 6) * 8;
        float s[8] = {0, 0, 0, 0, 0, 0, 0, 0};
#pragma unroll
        for (int w = 0; w < 4; ++w) {
            const float4 u = *(const float4*)&red[w][col][r0];
            const float4 v = *(const float4*)&red[w][col][r0 + 4];
            s[0] += u.x; s[1] += u.y; s[2] += u.z; s[3] += u.w;
            s[4] += v.x; s[5] += v.y; s[6] += v.z; s[7] += v.w;
        }
        if (nqb > 1) {
            float* np = numpart + ((size_t)q * NN + (size_t)rt * 32) * DD;
#pragma unroll
            for (int u2 = 0; u2 < 8; ++u2) np[(size_t)(r0 + u2) * DD + col] = s[u2];
        } else {
#pragma unroll
            for (int u2 = 0; u2 < 8; ++u2) {
                const int r = r0 + u2;
                const float inv = 1.0f / (zfin[0][r] * (zfin[1][r] * zfin[2][r]));
                out[(size_t)(rt * 32 + r) * DD + col] = s[u2] * inv;
            }
        }
    }
}

// Combine j-split partials (fixed order) — fallback path only.
__global__ __launch_bounds__(256) void mas_comb18(const float* __restrict__ numpart,
                                                  const float* __restrict__ zpart,
                                                  float* __restrict__ out, int nqb) {
    const int idx = blockIdx.x * 256 + threadIdx.x;
    const int i = idx >> 6;
    float s = 0.f;
    for (int q = 0; q < nqb; ++q) s += numpart[(size_t)q * NN * DD + idx];
    float Z0 = 0.f, Z1 = 0.f, Z2 = 0.f;
    for (int q = 0; q < nqb; ++q) {
        Z0 += zpart[((size_t)q * 3 + 0) * NN + i];
        Z1 += zpart[((size_t)q * 3 + 1) * NN + i];
        Z2 += zpart[((size_t)q * 3 + 2) * NN + i];
    }
    out[idx] = s / (Z0 * (Z1 * Z2));
}

extern "C" void kernel_launch(void* const* d_in, const int* in_sizes, int n_in,
                              void* d_out, int out_size, void* d_ws, size_t ws_size,
                              hipStream_t stream) {
    const float* X   = (const float*)d_in[0];
    // d_in[1] = A : unused by the reference computation (shape only)
    const float* Ws  = (const float*)d_in[2];
    const float* bWs = (const float*)d_in[3];
    const float* a1  = (const float*)d_in[4];
    const float* a2  = (const float*)d_in[5];
    const float* ba  = (const float*)d_in[6];
    float* out = (float*)d_out;

    float* Rt = (float*)d_ws;                    // [3][NN] f32
    _Float16* E2h  = (_Float16*)(Rt + NL * NN);  // [3][NN] f16
    _Float16* E2sh = E2h + NL * NN;              // [3][NN] f16
    _Float16* Xf   = E2sh + NL * NN;             // [NN*DD] f16 fragment order

    const size_t fixed = (size_t)NL * NN * 4 + (size_t)(2 * NL * NN) * 2
                       + (size_t)NN * DD * 2;
    const size_t per_q = (size_t)NN * DD * 4 + (size_t)NL * NN * 4;
    int nqb = 1;
    if (ws_size >= fixed + 4 * per_q + 1024) nqb = 4;
    else if (ws_size >= fixed + 2 * per_q + 1024) nqb = 2;

    float* numpart = (float*)(Xf + (size_t)NN * DD);  // [nqb][NN][DD]
    float* zpart   = numpart + (size_t)nqb * NN * DD; // [nqb][3][NN]
    int*   ticket  = (int*)(zpart + (size_t)nqb * NL * NN); // [128]

    mas_prep<<<352, 256, 0, stream>>>(X, Ws, bWs, a1, a2, ba, Rt, E2h, E2sh, Xf);
    if (nqb == 4) {
        hipMemsetAsync(ticket, 0, (NN / 64) * sizeof(int), stream);
        dim3 grid(NN / 64, 4);
        mas_main18<<<grid, 256, 0, stream>>>(Xf, Rt, E2h, E2sh,
                                             numpart, zpart, ticket, out);
    } else {
        dim3 grid(NN / 32, nqb);
        mas_main_fb<<<grid, 256, 0, stream>>>(Xf, Rt, E2h, E2sh,
                                              numpart, zpart, out, nqb);
        if (nqb > 1)
            mas_comb18<<<NN * DD / 256, 256, 0, stream>>>(numpart, zpart, out, nqb);
    }
}

// Round 19
// 52.969 us; speedup vs baseline: 1.8793x; 1.8793x over previous
//
#include <hip/hip_runtime.h>

#define NN 8192
#define DD 64
#define NL 3
#define LOG2E 1.4426950408889634f

typedef _Float16 f16x8 __attribute__((ext_vector_type(8)));
typedef _Float16 f16x2 __attribute__((ext_vector_type(2)));
typedef float f32x2 __attribute__((ext_vector_type(2)));
typedef float f32x16 __attribute__((ext_vector_type(16)));

union F16U { f16x8 v8; f16x2 h2[4]; };

// Prep kernel (unchanged).
//   a=(f1+ba)*log2e, b=f2*log2e
//   Rt[l][i]=2^(-0.8a) f32; E2h[l][j]=2^(b-4) f16; E2sh[l][j]=2^(0.2b-4) f16
//   e_l = 2^(a+4) * m_l, m_l = max(E2h, Rt*E2sh); row scale cancels exactly.
__global__ __launch_bounds__(256) void mas_prep(const float* __restrict__ X,
                                                const float* __restrict__ Ws,
                                                const float* __restrict__ bWs,
                                                const float* __restrict__ a1,
                                                const float* __restrict__ a2,
                                                const float* __restrict__ ba,
                                                float* __restrict__ Rt,
                                                _Float16* __restrict__ E2h,
                                                _Float16* __restrict__ E2sh,
                                                _Float16* __restrict__ Xf) {
    if (blockIdx.x < 96) {
        const int l = blockIdx.x >> 5;
        const int i = ((blockIdx.x & 31) << 8) + threadIdx.x;

        float xr[DD];
        const float4* X4 = (const float4*)(X + (size_t)i * DD);
#pragma unroll
        for (int q = 0; q < DD / 4; ++q) {
            float4 v = X4[q];
            xr[4 * q + 0] = v.x; xr[4 * q + 1] = v.y;
            xr[4 * q + 2] = v.z; xr[4 * q + 3] = v.w;
        }

        const float* W   = Ws  + l * DD * DD;
        const float* a1l = a1  + l * DD;
        const float* a2l = a2  + l * DD;
        const float* bwl = bWs + l * DD;

        float f1 = 0.f, f2 = 0.f;
#pragma unroll 4
        for (int d = 0; d < DD; ++d) {
            float wh = bwl[d];
            const float* wr = W + d * DD;
#pragma unroll
            for (int k = 0; k < DD; ++k) wh = fmaf(xr[k], wr[k], wh);
            f1 = fmaf(wh, a1l[d], f1);
            f2 = fmaf(wh, a2l[d], f2);
        }
        const float a = (f1 + ba[l]) * LOG2E;
        const float b = f2 * LOG2E;
        Rt  [l * NN + i] = exp2f(-0.8f * a);
        E2h [l * NN + i] = (_Float16)exp2f(b - 4.0f);
        E2sh[l * NN + i] = (_Float16)exp2f(0.2f * b - 4.0f);
    } else {
        const int t = (blockIdx.x - 96) * 256 + threadIdx.x;   // 0..65535
        const int lane = t & 63;
        const int st = t >> 6;
        const int S = st >> 1, tl = st & 1;
        const int d = tl * 32 + (lane & 31);
        const int j0 = S * 16 + (lane >> 5) * 8;
        f16x8 v;
#pragma unroll
        for (int e = 0; e < 8; ++e) v[e] = (_Float16)X[(size_t)(j0 + e) * DD + d];
        *(f16x8*)(Xf + (size_t)t * 8) = v;
    }
}

// Main v19 = R15 body EXACTLY, with launch_bounds relaxed (256,3)->(256,2):
// grid 512 = 2 blocks/CU regardless, so the only effect is VGPR cap 170->256,
// removing any silent spill the tighter bound may have forced.
template <int NQB>
__global__ __launch_bounds__(256, 2) void mas_main19(const _Float16* __restrict__ Xf,
                                                     const float* __restrict__ Rt,
                                                     const _Float16* __restrict__ E2h,
                                                     const _Float16* __restrict__ E2sh,
                                                     float* __restrict__ numpart,
                                                     float* __restrict__ zpart) {
    __shared__ float red[4][64][33];    // aliased as staged tables during loop
    __shared__ float zred[4][3][64];

    const int tid  = threadIdx.x;
    const int lane = tid & 63;
    const int wv   = tid >> 6;
    const int hi   = lane >> 5;
    const int row  = lane & 31;
    const int rt   = blockIdx.x;       // 64-row tile
    const int q    = blockIdx.y;
    const int iA   = rt * 64 + row;
    const int iB   = iA + 32;

#define MKP(x) {(_Float16)(x), (_Float16)(x)}
    const f16x2 R0A = MKP(Rt[0*NN+iA]), R1A = MKP(Rt[1*NN+iA]), R2A = MKP(Rt[2*NN+iA]);
    const f16x2 R0B = MKP(Rt[0*NN+iB]), R1B = MKP(Rt[1*NN+iB]), R2B = MKP(Rt[2*NN+iB]);
#undef MKP

    constexpr int jspan = NN / NQB;
    constexpr int wspan = jspan >> 2;
    constexpr int nst   = wspan >> 4;   // 32 at NQB=4
    const int jblk  = q * jspan;

    // ---- stage 6 table streams into LDS (6*jspan*2B = 24KB at NQB=4) ----
    _Float16* tab = (_Float16*)&red[0][0][0];
    {
        const _Float16* s0 = E2h  + 0 * NN + jblk;
        const _Float16* s1 = E2h  + 1 * NN + jblk;
        const _Float16* s2 = E2h  + 2 * NN + jblk;
        const _Float16* s3 = E2sh + 0 * NN + jblk;
        const _Float16* s4 = E2sh + 1 * NN + jblk;
        const _Float16* s5 = E2sh + 2 * NN + jblk;
        constexpr int nv = jspan >> 3;
#pragma unroll
        for (int v = 0; v < nv; v += 256) {
            const int u = v + tid;
            *(f16x8*)&tab[0 * jspan + u * 8] = *(const f16x8*)(s0 + u * 8);
            *(f16x8*)&tab[1 * jspan + u * 8] = *(const f16x8*)(s1 + u * 8);
            *(f16x8*)&tab[2 * jspan + u * 8] = *(const f16x8*)(s2 + u * 8);
            *(f16x8*)&tab[3 * jspan + u * 8] = *(const f16x8*)(s3 + u * 8);
            *(f16x8*)&tab[4 * jspan + u * 8] = *(const f16x8*)(s4 + u * 8);
            *(f16x8*)&tab[5 * jspan + u * 8] = *(const f16x8*)(s5 + u * 8);
        }
    }
    __syncthreads();

    const int tloc0 = wv * wspan + hi * 8;
    const f16x8* pB = (const f16x8*)Xf + (size_t)((jblk + wv * wspan) >> 4) * 128 + lane;

    f32x16 a00 = {}, a01 = {}, a10 = {}, a11 = {};
    f32x2 z0A = {0,0}, z1A = {0,0}, z2A = {0,0};
    f32x2 z0B = {0,0}, z1B = {0,0}, z2B = {0,0};

#pragma unroll 2
    for (int s = 0; s < nst; ++s) {
        const int o = tloc0 + s * 16;
        F16U g0, g1, g2, h0, h1, h2v;
        g0.v8  = *(const f16x8*)&tab[0 * jspan + o];
        g1.v8  = *(const f16x8*)&tab[1 * jspan + o];
        g2.v8  = *(const f16x8*)&tab[2 * jspan + o];
        h0.v8  = *(const f16x8*)&tab[3 * jspan + o];
        h1.v8  = *(const f16x8*)&tab[4 * jspan + o];
        h2v.v8 = *(const f16x8*)&tab[5 * jspan + o];
        const f16x8 vb0 = pB[s * 128];
        const f16x8 vb1 = pB[s * 128 + 64];

        // ---- half A ----
        {
            f16x2 m0[4], m1[4], m2[4];
#pragma unroll
            for (int g = 0; g < 4; ++g) {
                m0[g] = __builtin_elementwise_max(g0.h2[g], R0A * h0.h2[g]);
                m1[g] = __builtin_elementwise_max(g1.h2[g], R1A * h1.h2[g]);
                m2[g] = __builtin_elementwise_max(g2.h2[g], R2A * h2v.h2[g]);
            }
            const f16x2 t0 = (m0[0] + m0[1]) + (m0[2] + m0[3]);
            const f16x2 t1 = (m1[0] + m1[1]) + (m1[2] + m1[3]);
            const f16x2 t2 = (m2[0] + m2[1]) + (m2[2] + m2[3]);
            z0A += (f32x2){(float)t0[0], (float)t0[1]};
            z1A += (f32x2){(float)t1[0], (float)t1[1]};
            z2A += (f32x2){(float)t2[0], (float)t2[1]};
            F16U wa;
#pragma unroll
            for (int g = 0; g < 4; ++g) wa.h2[g] = m0[g] * (m1[g] * m2[g]);
            a00 = __builtin_amdgcn_mfma_f32_32x32x16_f16(wa.v8, vb0, a00, 0, 0, 0);
            a01 = __builtin_amdgcn_mfma_f32_32x32x16_f16(wa.v8, vb1, a01, 0, 0, 0);
        }
        // ---- half B ----
        {
            f16x2 m0[4], m1[4], m2[4];
#pragma unroll
            for (int g = 0; g < 4; ++g) {
                m0[g] = __builtin_elementwise_max(g0.h2[g], R0B * h0.h2[g]);
                m1[g] = __builtin_elementwise_max(g1.h2[g], R1B * h1.h2[g]);
                m2[g] = __builtin_elementwise_max(g2.h2[g], R2B * h2v.h2[g]);
            }
            const f16x2 t0 = (m0[0] + m0[1]) + (m0[2] + m0[3]);
            const f16x2 t1 = (m1[0] + m1[1]) + (m1[2] + m1[3]);
            const f16x2 t2 = (m2[0] + m2[1]) + (m2[2] + m2[3]);
            z0B += (f32x2){(float)t0[0], (float)t0[1]};
            z1B += (f32x2){(float)t1[0], (float)t1[1]};
            z2B += (f32x2){(float)t2[0], (float)t2[1]};
            F16U wa;
#pragma unroll
            for (int g = 0; g < 4; ++g) wa.h2[g] = m0[g] * (m1[g] * m2[g]);
            a10 = __builtin_amdgcn_mfma_f32_32x32x16_f16(wa.v8, vb0, a10, 0, 0, 0);
            a11 = __builtin_amdgcn_mfma_f32_32x32x16_f16(wa.v8, vb1, a11, 0, 0, 0);
        }
    }

    float z0a = z0A[0] + z0A[1], z1a = z1A[0] + z1A[1], z2a = z2A[0] + z2A[1];
    float z0b = z0B[0] + z0B[1], z1b = z1B[0] + z1B[1], z2b = z2B[0] + z2B[1];
    z0a += __shfl_xor(z0a, 32); z1a += __shfl_xor(z1a, 32); z2a += __shfl_xor(z2a, 32);
    z0b += __shfl_xor(z0b, 32); z1b += __shfl_xor(z1b, 32); z2b += __shfl_xor(z2b, 32);

    __syncthreads();   // all waves done reading tab before red is overwritten

    if (lane < 32) {
        zred[wv][0][row] = z0a; zred[wv][1][row] = z1a; zred[wv][2][row] = z2a;
        zred[wv][0][row + 32] = z0b; zred[wv][1][row + 32] = z1b; zred[wv][2][row + 32] = z2b;
    }

    // ---- epilogue pass 1: half A (global rows rt*64+0..31) ----
    // C row = (e&3)+8*(e>>2)+4*hi, C col = lane&31 (a00) / +32 (a01).
#pragma unroll
    for (int g = 0; g < 4; ++g) {
        const int rb = 8 * g + 4 * hi;
        *(float4*)&red[wv][row][rb] =
            make_float4(a00[4*g], a00[4*g+1], a00[4*g+2], a00[4*g+3]);
        *(float4*)&red[wv][row + 32][rb] =
            make_float4(a01[4*g], a01[4*g+1], a01[4*g+2], a01[4*g+3]);
    }
    __syncthreads();

    if (tid < 192) {
        const int l = tid >> 6, r = tid & 63;
        const float Z = zred[0][l][r] + zred[1][l][r] + zred[2][l][r] + zred[3][l][r];
        zpart[((size_t)q * 3 + l) * NN + rt * 64 + r] = Z;
    }

    {
        const int col = tid & 63;
        const int r0 = (tid >> 6) * 8;
        float s[8] = {0,0,0,0,0,0,0,0};
#pragma unroll
        for (int w = 0; w < 4; ++w) {
            const float4 u = *(const float4*)&red[w][col][r0];
            const float4 v = *(const float4*)&red[w][col][r0 + 4];
            s[0] += u.x; s[1] += u.y; s[2] += u.z; s[3] += u.w;
            s[4] += v.x; s[5] += v.y; s[6] += v.z; s[7] += v.w;
        }
        float* np = numpart + (size_t)q * NN * DD;
#pragma unroll
        for (int u2 = 0; u2 < 8; ++u2)
            np[(size_t)(rt * 64 + r0 + u2) * DD + col] = s[u2];
    }
    __syncthreads();

    // ---- epilogue pass 2: half B (global rows rt*64+32..63) ----
#pragma unroll
    for (int g = 0; g < 4; ++g) {
        const int rb = 8 * g + 4 * hi;
        *(float4*)&red[wv][row][rb] =
            make_float4(a10[4*g], a10[4*g+1], a10[4*g+2], a10[4*g+3]);
        *(float4*)&red[wv][row + 32][rb] =
            make_float4(a11[4*g], a11[4*g+1], a11[4*g+2], a11[4*g+3]);
    }
    __syncthreads();

    {
        const int col = tid & 63;
        const int r0 = (tid >> 6) * 8;
        float s[8] = {0,0,0,0,0,0,0,0};
#pragma unroll
        for (int w = 0; w < 4; ++w) {
            const float4 u = *(const float4*)&red[w][col][r0];
            const float4 v = *(const float4*)&red[w][col][r0 + 4];
            s[0] += u.x; s[1] += u.y; s[2] += u.z; s[3] += u.w;
            s[4] += v.x; s[5] += v.y; s[6] += v.z; s[7] += v.w;
        }
        float* np = numpart + (size_t)q * NN * DD;
#pragma unroll
        for (int u2 = 0; u2 < 8; ++u2)
            np[(size_t)(rt * 64 + 32 + r0 + u2) * DD + col] = s[u2];
    }
}

// Fallback main (runtime nqb, VMEM tables) for small-ws case.
__global__ __launch_bounds__(256, 4) void mas_main_fb(const _Float16* __restrict__ Xf,
                                                      const float* __restrict__ Rt,
                                                      const _Float16* __restrict__ E2h,
                                                      const _Float16* __restrict__ E2sh,
                                                      float* __restrict__ numpart,
                                                      float* __restrict__ zpart,
                                                      float* __restrict__ out,
                                                      int nqb) {
    __shared__ float red[4][64][33];
    __shared__ float zred[4][3][32];
    __shared__ float zfin[3][32];

    const int tid  = threadIdx.x;
    const int lane = tid & 63;
    const int wv   = tid >> 6;
    const int hi   = lane >> 5;
    const int row  = lane & 31;
    const int rt   = blockIdx.x;
    const int q    = blockIdx.y;
    const int i    = rt * 32 + row;

    const float r0f = Rt[0 * NN + i], r1f = Rt[1 * NN + i], r2f = Rt[2 * NN + i];
    const f16x2 R0p = {(_Float16)r0f, (_Float16)r0f};
    const f16x2 R1p = {(_Float16)r1f, (_Float16)r1f};
    const f16x2 R2p = {(_Float16)r2f, (_Float16)r2f};

    const int jspan = NN / nqb;
    const int wspan = jspan >> 2;
    const int jbase = q * jspan + wv * wspan;
    const int nst   = wspan >> 4;

    const _Float16* q20 = E2h  + 0 * NN + jbase + hi * 8;
    const _Float16* q21 = E2h  + 1 * NN + jbase + hi * 8;
    const _Float16* q22 = E2h  + 2 * NN + jbase + hi * 8;
    const _Float16* r20 = E2sh + 0 * NN + jbase + hi * 8;
    const _Float16* r21 = E2sh + 1 * NN + jbase + hi * 8;
    const _Float16* r22 = E2sh + 2 * NN + jbase + hi * 8;
    const f16x8* pB = (const f16x8*)Xf + (size_t)(jbase >> 4) * 128 + lane;

    f32x16 acc0 = {};
    f32x16 acc1 = {};
    f32x2 z0p = {0.f, 0.f}, z1p = {0.f, 0.f}, z2p = {0.f, 0.f};

    for (int s = 0; s < nst; ++s) {
        const int o = s * 16;
        F16U g0, g1, g2, h0, h1, h2v;
        g0.v8  = *(const f16x8*)(q20 + o);
        g1.v8  = *(const f16x8*)(q21 + o);
        g2.v8  = *(const f16x8*)(q22 + o);
        h0.v8  = *(const f16x8*)(r20 + o);
        h1.v8  = *(const f16x8*)(r21 + o);
        h2v.v8 = *(const f16x8*)(r22 + o);
        const f16x8 vb0 = pB[s * 128];
        const f16x8 vb1 = pB[s * 128 + 64];

        f16x2 m0[4], m1[4], m2[4];
#pragma unroll
        for (int g = 0; g < 4; ++g) {
            m0[g] = __builtin_elementwise_max(g0.h2[g], R0p * h0.h2[g]);
            m1[g] = __builtin_elementwise_max(g1.h2[g], R1p * h1.h2[g]);
            m2[g] = __builtin_elementwise_max(g2.h2[g], R2p * h2v.h2[g]);
        }
        const f16x2 t0 = (m0[0] + m0[1]) + (m0[2] + m0[3]);
        const f16x2 t1 = (m1[0] + m1[1]) + (m1[2] + m1[3]);
        const f16x2 t2 = (m2[0] + m2[1]) + (m2[2] + m2[3]);
        z0p += (f32x2){(float)t0[0], (float)t0[1]};
        z1p += (f32x2){(float)t1[0], (float)t1[1]};
        z2p += (f32x2){(float)t2[0], (float)t2[1]};

        F16U wa;
#pragma unroll
        for (int g = 0; g < 4; ++g) wa.h2[g] = m0[g] * (m1[g] * m2[g]);

        acc0 = __builtin_amdgcn_mfma_f32_32x32x16_f16(wa.v8, vb0, acc0, 0, 0, 0);
        acc1 = __builtin_amdgcn_mfma_f32_32x32x16_f16(wa.v8, vb1, acc1, 0, 0, 0);
    }

    float z0 = z0p[0] + z0p[1];
    float z1 = z1p[0] + z1p[1];
    float z2 = z2p[0] + z2p[1];
    z0 += __shfl_xor(z0, 32);
    z1 += __shfl_xor(z1, 32);
    z2 += __shfl_xor(z2, 32);

#pragma unroll
    for (int g = 0; g < 4; ++g) {
        const int rb = 8 * g + 4 * hi;
        *(float4*)&red[wv][row][rb] =
            make_float4(acc0[4 * g], acc0[4 * g + 1], acc0[4 * g + 2], acc0[4 * g + 3]);
        *(float4*)&red[wv][row + 32][rb] =
            make_float4(acc1[4 * g], acc1[4 * g + 1], acc1[4 * g + 2], acc1[4 * g + 3]);
    }
    if (lane < 32) {
        zred[wv][0][row] = z0; zred[wv][1][row] = z1; zred[wv][2][row] = z2;
    }
    __syncthreads();

    if (tid < 96) {
        const int l = tid >> 5, r = tid & 31;
        const float Z = zred[0][l][r] + zred[1][l][r] + zred[2][l][r] + zred[3][l][r];
        if (nqb > 1) zpart[((size_t)q * 3 + l) * NN + rt * 32 + r] = Z;
        else zfin[l][r] = Z;
    }
    __syncthreads();

    {
        const int col = tid & 63;
        const int r0 = (tid >> 6) * 8;
        float s[8] = {0, 0, 0, 0, 0, 0, 0, 0};
#pragma unroll
        for (int w = 0; w < 4; ++w) {
            const float4 u = *(const float4*)&red[w][col][r0];
            const float4 v = *(const float4*)&red[w][col][r0 + 4];
            s[0] += u.x; s[1] += u.y; s[2] += u.z; s[3] += u.w;
            s[4] += v.x; s[5] += v.y; s[6] += v.z; s[7] += v.w;
        }
        if (nqb > 1) {
            float* np = numpart + ((size_t)q * NN + (size_t)rt * 32) * DD;
#pragma unroll
            for (int u2 = 0; u2 < 8; ++u2) np[(size_t)(r0 + u2) * DD + col] = s[u2];
        } else {
#pragma unroll
            for (int u2 = 0; u2 < 8; ++u2) {
                const int r = r0 + u2;
                const float inv = 1.0f / (zfin[0][r] * (zfin[1][r] * zfin[2][r]));
                out[(size_t)(rt * 32 + r) * DD + col] = s[u2] * inv;
            }
        }
    }
}

// Combine j-split partials (fixed order, deterministic). Row scales cancel.
__global__ __launch_bounds__(256) void mas_comb19(const float* __restrict__ numpart,
                                                  const float* __restrict__ zpart,
                                                  float* __restrict__ out, int nqb) {
    const int idx = blockIdx.x * 256 + threadIdx.x;
    const int i = idx >> 6;
    float s = 0.f;
    for (int q = 0; q < nqb; ++q) s += numpart[(size_t)q * NN * DD + idx];
    float Z0 = 0.f, Z1 = 0.f, Z2 = 0.f;
    for (int q = 0; q < nqb; ++q) {
        Z0 += zpart[((size_t)q * 3 + 0) * NN + i];
        Z1 += zpart[((size_t)q * 3 + 1) * NN + i];
        Z2 += zpart[((size_t)q * 3 + 2) * NN + i];
    }
    out[idx] = s / (Z0 * (Z1 * Z2));
}

extern "C" void kernel_launch(void* const* d_in, const int* in_sizes, int n_in,
                              void* d_out, int out_size, void* d_ws, size_t ws_size,
                              hipStream_t stream) {
    const float* X   = (const float*)d_in[0];
    // d_in[1] = A : unused by the reference computation (shape only)
    const float* Ws  = (const float*)d_in[2];
    const float* bWs = (const float*)d_in[3];
    const float* a1  = (const float*)d_in[4];
    const float* a2  = (const float*)d_in[5];
    const float* ba  = (const float*)d_in[6];
    float* out = (float*)d_out;

    float* Rt = (float*)d_ws;                    // [3][NN] f32
    _Float16* E2h  = (_Float16*)(Rt + NL * NN);  // [3][NN] f16
    _Float16* E2sh = E2h + NL * NN;              // [3][NN] f16
    _Float16* Xf   = E2sh + NL * NN;             // [NN*DD] f16 fragment order

    const size_t fixed = (size_t)NL * NN * 4 + (size_t)(2 * NL * NN) * 2
                       + (size_t)NN * DD * 2;
    const size_t per_q = (size_t)NN * DD * 4 + (size_t)NL * NN * 4;
    int nqb = 1;
    if (ws_size >= fixed + 4 * per_q) nqb = 4;
    else if (ws_size >= fixed + 2 * per_q) nqb = 2;

    float* numpart = (float*)(Xf + (size_t)NN * DD);  // [nqb][NN][DD]
    float* zpart   = numpart + (size_t)nqb * NN * DD; // [nqb][3][NN]

    mas_prep<<<352, 256, 0, stream>>>(X, Ws, bWs, a1, a2, ba, Rt, E2h, E2sh, Xf);
    if (nqb == 4) {
        dim3 grid(NN / 64, 4);
        mas_main19<4><<<grid, 256, 0, stream>>>(Xf, Rt, E2h, E2sh, numpart, zpart);
        mas_comb19<<<NN * DD / 256, 256, 0, stream>>>(numpart, zpart, out, 4);
    } else {
        dim3 grid(NN / 32, nqb);
        mas_main_fb<<<grid, 256, 0, stream>>>(Xf, Rt, E2h, E2sh,
                                              numpart, zpart, out, nqb);
        if (nqb > 1)
            mas_comb19<<<NN * DD / 256, 256, 0, stream>>>(numpart, zpart, out, nqb);
    }
}